// Round 3
// baseline (1615.318 us; speedup 1.0000x reference)
//
#include <hip/hip_runtime.h>
#include <stdint.h>

#define NE    33554432   // 16384*32*64  elements of each (B,W,64) tensor
#define MROWS 524288     // B*W rows of the cat matrix

typedef __attribute__((ext_vector_type(8))) short short8;
typedef __attribute__((ext_vector_type(4))) float f32x4;
typedef unsigned short ushort_t;
typedef unsigned char uchar_t;

// ---------- helpers ----------
__device__ __forceinline__ unsigned fenc(float f){
  unsigned u=__float_as_uint(f); return (u&0x80000000u)?~u:(u|0x80000000u);
}
__device__ __forceinline__ float fdec(unsigned u){
  return __uint_as_float((u&0x80000000u)?(u&0x7fffffffu):~u);
}
__device__ __forceinline__ void obs(float mn,float mx,float&s,float&zp){
  mn=fminf(mn,0.f); mx=fmaxf(mx,0.f);
  s=fmaxf((mx-mn)/255.0f,1e-8f);
  zp=fminf(fmaxf(rintf(-128.0f-mn/s),-128.f),127.f);
}
__device__ __forceinline__ float qof(float x,float s,float zp){   // quantized code (as float)
  return fminf(fmaxf(rintf(x/s)+zp,-128.f),127.f);
}
__device__ __forceinline__ float fqv(float x,float s,float zp){   // dequantized value
  return (qof(x,s,zp)-zp)*s;
}
__device__ __forceinline__ void wred(float&mn,float&mx){
  #pragma unroll
  for(int o=32;o;o>>=1){mn=fminf(mn,__shfl_xor(mn,o));mx=fmaxf(mx,__shfl_xor(mx,o));}
}
// derive gate-g stage-0 scales from U (identical math to old k_post stage 0)
__device__ __forceinline__ void stage0(const unsigned* U,int g,float&s1,float&z1,float&s2,float&z2){
  float mn=fdec(U[6+2*g]),mx=fdec(U[7+2*g]);
  obs(mn,mx,s1,z1);
  float gmn=fqv(mn,s1,z1),gmx=fqv(mx,s1,z1);
  float amn,amx;
  if(g==3){amn=fminf(fmaxf(gmn,-1.f),1.f);amx=fminf(fmaxf(gmx,-1.f),1.f);}
  else{amn=fminf(fmaxf(gmn/6.0f+0.5f,0.f),1.f);amx=fminf(fmaxf(gmx/6.0f+0.5f,0.f),1.f);}
  obs(amn,amx,s2,z2);
}
__device__ __forceinline__ float lut_entry(int t,int g,float s1,float z1,float s2,float z2){
  float g1=((float)(t-128)-z1)*s1;
  float a=(g==3)?fminf(fmaxf(g1,-1.f),1.f):fminf(fmaxf(g1/6.0f+0.5f,0.f),1.f);
  return fqv(a,s2,z2);
}
// derive cn/ct scales from U (identical math to old k_post stage 2)
__device__ __forceinline__ void stage2v(const unsigned* U,float&scn,float&zcn,float&sct,float&zct){
  float mn=fdec(U[18]),mx=fdec(U[19]);
  obs(mn,mx,scn,zcn);
  float tmn=fminf(fmaxf(fqv(mn,scn,zcn),-1.f),1.f);
  float tmx=fminf(fmaxf(fqv(mx,scn,zcn),-1.f),1.f);
  obs(tmn,tmx,sct,zct);
}

// U layout: 0,1 x | 2,3 h | 4,5 c | 6..13 gates(i,f,o,cg) | 14,15 fc | 16,17 ic | 18,19 cn | 20,21 hn
// S layout: 0-5 sx,zx,sh,zh,sc,zc | 6,7 scat,zcat | 8-15 sW[g],zW[g]

__global__ void k0_init(unsigned* U){
  int t=threadIdx.x;
  if(t<11){U[2*t]=0xFFFFFFFFu;U[2*t+1]=0u;}
}

__global__ __launch_bounds__(256) void k1_minmax(const float* __restrict__ x,
    const float* __restrict__ h,const float* __restrict__ c,unsigned* U){
  __shared__ float red[8];
  int t=blockIdx.x*256+threadIdx.x, stride=gridDim.x*256;
  int w=threadIdx.x>>6,l=threadIdx.x&63;
  const float4* ps[3]={(const float4*)x,(const float4*)h,(const float4*)c};
  for(int q=0;q<3;q++){
    float mn=3.4e38f,mx=-3.4e38f;
    const float4* p=ps[q];
    for(int e=t;e<NE/4;e+=4*stride){      // NE/4 divisible by 4*stride for grid 2048
      float4 a=p[e],b=p[e+stride],c4=p[e+2*stride],d=p[e+3*stride];
      mn=fminf(mn,fminf(fminf(a.x,a.y),fminf(a.z,a.w)));
      mx=fmaxf(mx,fmaxf(fmaxf(a.x,a.y),fmaxf(a.z,a.w)));
      mn=fminf(mn,fminf(fminf(b.x,b.y),fminf(b.z,b.w)));
      mx=fmaxf(mx,fmaxf(fmaxf(b.x,b.y),fmaxf(b.z,b.w)));
      mn=fminf(mn,fminf(fminf(c4.x,c4.y),fminf(c4.z,c4.w)));
      mx=fmaxf(mx,fmaxf(fmaxf(c4.x,c4.y),fmaxf(c4.z,c4.w)));
      mn=fminf(mn,fminf(fminf(d.x,d.y),fminf(d.z,d.w)));
      mx=fmaxf(mx,fmaxf(fmaxf(d.x,d.y),fmaxf(d.z,d.w)));
    }
    wred(mn,mx);
    if(l==0){red[w]=mn;red[4+w]=mx;}
    __syncthreads();
    if(threadIdx.x==0){
      float bmn=fminf(fminf(red[0],red[1]),fminf(red[2],red[3]));
      float bmx=fmaxf(fmaxf(red[4],red[5]),fmaxf(red[6],red[7]));
      atomicMin(&U[2*q],fenc(bmn)); atomicMax(&U[2*q+1],fenc(bmx));
    }
    __syncthreads();
  }
}

// scalars for x/h/c/cat + cat LUTs + per-gate weight/bias quantization (single block)
__global__ __launch_bounds__(256) void k2_prep(const float* Wi,const float* bi,
    const float* Wf,const float* bfv,const float* Wo,const float* bo,
    const float* Wcg,const float* bcg,
    const unsigned* U,float* S,ushort_t* Wc,float* bq,ushort_t* LUTcx){
  __shared__ float smn[256],smx[256],sP[4],sS[8];
  int t=threadIdx.x;
  if(t==0){
    float xmn=fdec(U[0]),xmx=fdec(U[1]),hmn=fdec(U[2]),hmx=fdec(U[3]),cmn=fdec(U[4]),cmx=fdec(U[5]);
    float sx,zx,sh,zh,sc,zc;
    obs(xmn,xmx,sx,zx);obs(hmn,hmx,sh,zh);obs(cmn,cmx,sc,zc);
    S[0]=sx;S[1]=zx;S[2]=sh;S[3]=zh;S[4]=sc;S[5]=zc;
    sS[0]=sx;sS[1]=zx;sS[2]=sh;sS[3]=zh;sS[4]=sc;sS[5]=zc;
    float cmn2=fminf(fqv(xmn,sx,zx),fqv(hmn,sh,zh));
    float cmx2=fmaxf(fqv(xmx,sx,zx),fqv(hmx,sh,zh));
    float scat,zcat;obs(cmn2,cmx2,scat,zcat);S[6]=scat;S[7]=zcat;
    sS[6]=scat;sS[7]=zcat;
  }
  __syncthreads();
  { // exact cat-code LUTs: inner code -> centered bf16 cat code
    float sx=sS[0],zx=sS[1],sh=sS[2],zh=sS[3],scat=sS[6],zcat=sS[7];
    float cx=qof(((float)(t-128)-zx)*sx,scat,zcat)-zcat;
    float ch=qof(((float)(t-128)-zh)*sh,scat,zcat)-zcat;
    LUTcx[t]    =(ushort_t)(__float_as_uint(cx)>>16);
    LUTcx[256+t]=(ushort_t)(__float_as_uint(ch)>>16);
  }
  const float* Wp[4]={Wi,Wf,Wo,Wcg};
  const float* bp[4]={bi,bfv,bo,bcg};
  for(int g=0;g<4;g++){
    float mn=3.4e38f,mx=-3.4e38f;
    for(int i=t;i<8192;i+=256){float v=Wp[g][i];mn=fminf(mn,v);mx=fmaxf(mx,v);}
    smn[t]=mn;smx[t]=mx;__syncthreads();
    for(int ss=128;ss;ss>>=1){
      if(t<ss){smn[t]=fminf(smn[t],smn[t+ss]);smx[t]=fmaxf(smx[t],smx[t+ss]);}
      __syncthreads();
    }
    if(t==0){
      float s_,z_;obs(smn[0],smx[0],s_,z_);
      S[8+2*g]=s_;S[9+2*g]=z_;sP[0]=s_;sP[1]=z_;
      float bmn=3.4e38f,bmx=-3.4e38f;
      for(int i=0;i<64;i++){float v=bp[g][i];bmn=fminf(bmn,v);bmx=fmaxf(bmx,v);}
      float sb,zb;obs(bmn,bmx,sb,zb);sP[2]=sb;sP[3]=zb;
    }
    __syncthreads();
    float s_=sP[0],z_=sP[1],sb=sP[2],zb=sP[3];
    for(int i=t;i<8192;i+=256){
      float cv=qof(Wp[g][i],s_,z_)-z_;                 // centered integer, exact in bf16
      Wc[g*8192+i]=(ushort_t)(__float_as_uint(cv)>>16);
    }
    if(t<64) bq[g*64+t]=fqv(bp[g][t],sb,zb);
    __syncthreads();
  }
}

// quantize: cat -> centered bf16 via LUT (1 divide/elem), c -> biased int8 codes
__global__ __launch_bounds__(256) void k3_quant(const float* __restrict__ x,
    const float* __restrict__ h,const float* __restrict__ c,
    const float* __restrict__ S,const ushort_t* __restrict__ LUTcx,
    ushort_t* __restrict__ catc,uchar_t* __restrict__ qc){
  __shared__ ushort_t lcx[512];
  int tid=threadIdx.x;
  for(int i=tid;i<512;i+=256) lcx[i]=LUTcx[i];
  float sx=S[0],zx=S[1],sh=S[2],zh=S[3],sc=S[4],zc=S[5];
  __syncthreads();
  int t=blockIdx.x*256+tid, stride=gridDim.x*256;
  const float4* xp=(const float4*)x; const float4* hp=(const float4*)h;
  for(int e=t;e<MROWS*32;e+=stride){      // 32 float4 per 128-wide row
    int row=e>>5,k4=e&31;
    float4 v; float s1,z1; int off;
    if(k4<16){v=xp[row*16+k4];s1=sx;z1=zx;off=0;}
    else     {v=hp[row*16+(k4-16)];s1=sh;z1=zh;off=256;}
    int q0=(int)qof(v.x,s1,z1)+128;
    int q1=(int)qof(v.y,s1,z1)+128;
    int q2=(int)qof(v.z,s1,z1)+128;
    int q3=(int)qof(v.w,s1,z1)+128;
    uint2 o;
    o.x=(unsigned)lcx[off+q0]|((unsigned)lcx[off+q1]<<16);
    o.y=(unsigned)lcx[off+q2]|((unsigned)lcx[off+q3]<<16);
    ((uint2*)catc)[e]=o;
  }
  const float4* cp=(const float4*)c;
  unsigned* qcp=(unsigned*)qc;
  for(int e=t;e<NE/4;e+=stride){
    float4 v=cp[e];
    int q0=(int)qof(v.x,sc,zc)+128,q1=(int)qof(v.y,sc,zc)+128;
    int q2=(int)qof(v.z,sc,zc)+128,q3=(int)qof(v.w,sc,zc)+128;
    qcp[e]=(unsigned)q0|((unsigned)q1<<8)|((unsigned)q2<<16)|((unsigned)q3<<24);
  }
}

// GEMM pass A: gate pre-act minmax. Per-nt acc minmax, affine folded after (exact:
// v=sgp*acc+bqr is monotone in acc since sgp>0, fp rounding is monotone).
__global__ __launch_bounds__(256,4) void g0_minmax(const ushort_t* __restrict__ catc,
    const ushort_t* __restrict__ Wc,const float* __restrict__ S,
    const float* __restrict__ bq,unsigned* U){
  int tid=threadIdx.x,w=tid>>6,l=tid&63,l15=l&15,lq=l>>4;
  float sgp=S[6]*S[8+2*w];                   // s_cat * s_w[gate]
  short8 bf[4][4];
  #pragma unroll
  for(int nt=0;nt<4;nt++)
    #pragma unroll
    for(int ks=0;ks<4;ks++)
      bf[nt][ks]=*(const short8*)(Wc+w*8192+(nt*16+l15)*128+ks*32+lq*8);
  float bqr[4];
  #pragma unroll
  for(int nt=0;nt<4;nt++) bqr[nt]=bq[w*64+nt*16+l15];
  float mnA[4],mxA[4];
  #pragma unroll
  for(int nt=0;nt<4;nt++){mnA[nt]=3.4e38f;mxA[nt]=-3.4e38f;}
  for(int u=0;u<8;u++){                      // 2 groups x 4 row-tiles
    int grp=blockIdx.x*2+(u>>2), mt=u&3;
    const ushort_t* arow=catc+(size_t)(grp*64+mt*16+l15)*128;
    short8 af[4];
    #pragma unroll
    for(int ks=0;ks<4;ks++) af[ks]=*(const short8*)(arow+ks*32+lq*8);
    f32x4 acc[4];
    #pragma unroll
    for(int nt=0;nt<4;nt++) acc[nt]=(f32x4){0.f,0.f,0.f,0.f};
    #pragma unroll
    for(int ks=0;ks<4;ks++)
      #pragma unroll
      for(int nt=0;nt<4;nt++)
        acc[nt]=__builtin_amdgcn_mfma_f32_16x16x32_bf16(af[ks],bf[nt][ks],acc[nt],0,0,0);
    #pragma unroll
    for(int nt=0;nt<4;nt++)
      #pragma unroll
      for(int r=0;r<4;r++){
        mnA[nt]=fminf(mnA[nt],acc[nt][r]);
        mxA[nt]=fmaxf(mxA[nt],acc[nt][r]);
      }
  }
  float mn=3.4e38f,mx=-3.4e38f;
  #pragma unroll
  for(int nt=0;nt<4;nt++){
    mn=fminf(mn,sgp*mnA[nt]+bqr[nt]);
    mx=fmaxf(mx,sgp*mxA[nt]+bqr[nt]);
  }
  wred(mn,mx);
  if(l==0){atomicMin(&U[6+2*w],fenc(mn));atomicMax(&U[7+2*w],fenc(mx));}
}

// GEMM pass B: quantize pre-acts to codes once, store packed codes, fc/ic minmax via LUT.
// 32-row exchange tile (padded to 66 -> <=2-way write conflicts) ~38KB LDS -> 4 blocks/CU.
__global__ __launch_bounds__(256,4) void g1_codes(const ushort_t* __restrict__ catc,
    const ushort_t* __restrict__ Wc,const float* __restrict__ S,
    const float* __restrict__ bq,const uchar_t* __restrict__ qc,
    unsigned* U,unsigned* __restrict__ qpack,uchar_t* __restrict__ qo){
  __shared__ float ldsq[4][32][66];
  __shared__ float lut[1024];
  __shared__ float red[16];
  int tid=threadIdx.x,w=tid>>6,l=tid&63,l15=l&15,lq=l>>4;
  float sg1,zg1;
  #pragma unroll
  for(int g=0;g<4;g++){
    float s1,z1,s2,z2; stage0(U,g,s1,z1,s2,z2);
    if(g==w){sg1=s1;zg1=z1;}
    lut[g*256+tid]=lut_entry(tid,g,s1,z1,s2,z2);
  }
  float sgp=S[6]*S[8+2*w];
  float sc=S[4],zc128=S[5]+128.0f;
  short8 bf[4][4];
  #pragma unroll
  for(int nt=0;nt<4;nt++)
    #pragma unroll
    for(int ks=0;ks<4;ks++)
      bf[nt][ks]=*(const short8*)(Wc+w*8192+(nt*16+l15)*128+ks*32+lq*8);
  float bqr[4];
  #pragma unroll
  for(int nt=0;nt<4;nt++) bqr[nt]=bq[w*64+nt*16+l15];
  __syncthreads();
  float fmn=3.4e38f,fmx=-3.4e38f,imn=3.4e38f,imx=-3.4e38f;
  for(int gi=0;gi<4;gi++){
    int grp=blockIdx.x*4+gi;
    #pragma unroll
    for(int half=0;half<2;half++){
      #pragma unroll
      for(int mt2=0;mt2<2;mt2++){
        int mt=half*2+mt2;
        const ushort_t* arow=catc+(size_t)(grp*64+mt*16+l15)*128;
        short8 af[4];
        #pragma unroll
        for(int ks=0;ks<4;ks++) af[ks]=*(const short8*)(arow+ks*32+lq*8);
        f32x4 acc[4];
        #pragma unroll
        for(int nt=0;nt<4;nt++) acc[nt]=(f32x4){0.f,0.f,0.f,0.f};
        #pragma unroll
        for(int ks=0;ks<4;ks++)
          #pragma unroll
          for(int nt=0;nt<4;nt++)
            acc[nt]=__builtin_amdgcn_mfma_f32_16x16x32_bf16(af[ks],bf[nt][ks],acc[nt],0,0,0);
        #pragma unroll
        for(int nt=0;nt<4;nt++)
          #pragma unroll
          for(int r=0;r<4;r++)
            ldsq[w][mt2*16+lq*4+r][nt*16+l15]=qof(sgp*acc[nt][r]+bqr[nt],sg1,zg1);
      }
      __syncthreads();
      #pragma unroll
      for(int it=0;it<2;it++){
        int e4=(tid+it*256)<<2;                 // 0..2044 within half-tile
        int gidx=grp*4096+half*2048+e4;
        unsigned qcw=*(const unsigned*)(qc+gidx);
        uint4 qp; unsigned qob=0;
        #pragma unroll
        for(int j=0;j<4;j++){
          int row=(e4+j)>>6, col=(e4+j)&63;
          int q0=(int)ldsq[0][row][col]+128;    // i
          int q1=(int)ldsq[1][row][col]+128;    // f
          int q2=(int)ldsq[2][row][col]+128;    // o
          int q3=(int)ldsq[3][row][col]+128;    // cg
          int qcb=(int)((qcw>>(8*j))&255);
          ((unsigned*)&qp)[j]=(unsigned)q0|((unsigned)q1<<8)|((unsigned)q3<<16)|((unsigned)qcb<<24);
          qob|=(unsigned)q2<<(8*j);
          float avi=lut[q0],avf=lut[256+q1],avcg=lut[768+q3];
          float cv=((float)qcb-zc128)*sc;
          float fc=avf*cv,ic=avi*avcg;
          fmn=fminf(fmn,fc);fmx=fmaxf(fmx,fc);
          imn=fminf(imn,ic);imx=fmaxf(imx,ic);
        }
        *(uint4*)(qpack+gidx)=qp;
        *(unsigned*)(qo+gidx)=qob;
      }
      __syncthreads();
    }
  }
  wred(fmn,fmx);wred(imn,imx);
  if(l==0){red[w]=fmn;red[4+w]=fmx;red[8+w]=imn;red[12+w]=imx;}
  __syncthreads();
  if(tid==0){
    float a=fminf(fminf(red[0],red[1]),fminf(red[2],red[3]));
    float b=fmaxf(fmaxf(red[4],red[5]),fmaxf(red[6],red[7]));
    atomicMin(&U[14],fenc(a));atomicMax(&U[15],fenc(b));
    a=fminf(fminf(red[8],red[9]),fminf(red[10],red[11]));
    b=fmaxf(fmaxf(red[12],red[13]),fmaxf(red[14],red[15]));
    atomicMin(&U[16],fenc(a));atomicMax(&U[17],fenc(b));
  }
}

// elementwise: cn minmax + fc/ic codes (x4 vectorized, scales derived from U)
__global__ __launch_bounds__(256) void e2_cn(const unsigned* __restrict__ qpack,
    const float* __restrict__ S,unsigned* U,ushort_t* __restrict__ qfcic){
  __shared__ float lut[1024];
  __shared__ float red[8];
  int tid=threadIdx.x;
  #pragma unroll
  for(int g=0;g<4;g++){
    float s1,z1,s2,z2; stage0(U,g,s1,z1,s2,z2);
    lut[g*256+tid]=lut_entry(tid,g,s1,z1,s2,z2);
  }
  float sfc,zfc,sic,zic;
  obs(fdec(U[14]),fdec(U[15]),sfc,zfc);
  obs(fdec(U[16]),fdec(U[17]),sic,zic);
  float sc=S[4],zc128=S[5]+128.0f;
  __syncthreads();
  float mn=3.4e38f,mx=-3.4e38f;
  int t=blockIdx.x*256+tid,stride=gridDim.x*256;
  const uint4* qp4=(const uint4*)qpack;
  uint2* qf2=(uint2*)qfcic;
  for(int e=t;e<NE/4;e+=stride){
    uint4 u4=qp4[e];
    unsigned lo=0,hi=0;
    #pragma unroll
    for(int j=0;j<4;j++){
      unsigned u=((const unsigned*)&u4)[j];
      int q0=u&255,q1=(u>>8)&255,q3=(u>>16)&255,qcb=u>>24;
      float avi=lut[q0],avf=lut[256+q1],avcg=lut[768+q3];
      float cv=((float)qcb-zc128)*sc;
      float fc=avf*cv,ic=avi*avcg;
      float qfc=qof(fc,sfc,zfc),qic=qof(ic,sic,zic);
      float cn=(qfc-zfc)*sfc+(qic-zic)*sic;
      mn=fminf(mn,cn);mx=fmaxf(mx,cn);
      unsigned pk=(unsigned)((int)qfc+128)|((unsigned)((int)qic+128)<<8);
      if(j<2) lo|=pk<<(16*j); else hi|=pk<<(16*(j-2));
    }
    uint2 o; o.x=lo; o.y=hi;
    qf2[e]=o;
  }
  int w=tid>>6,l=tid&63;
  wred(mn,mx);
  if(l==0){red[w]=mn;red[4+w]=mx;}
  __syncthreads();
  if(tid==0){
    float a=fminf(fminf(red[0],red[1]),fminf(red[2],red[3]));
    float b=fmaxf(fmaxf(red[4],red[5]),fmaxf(red[6],red[7]));
    atomicMin(&U[18],fenc(a));atomicMax(&U[19],fenc(b));
  }
}

// elementwise: c_next codes + h_raw minmax (x4 vectorized, scales/LUTs from U)
__global__ __launch_bounds__(256) void e3_hmm(const ushort_t* __restrict__ qfcic,
    const uchar_t* __restrict__ qo,unsigned* U,uchar_t* __restrict__ qcn){
  __shared__ float lao[256],lct[256];
  __shared__ float red[8];
  int tid=threadIdx.x;
  {
    float s1,z1,s2,z2; stage0(U,2,s1,z1,s2,z2);
    lao[tid]=lut_entry(tid,2,s1,z1,s2,z2);
  }
  float sfc,zfc,sic,zic;
  obs(fdec(U[14]),fdec(U[15]),sfc,zfc);
  obs(fdec(U[16]),fdec(U[17]),sic,zic);
  float scn,zcn,sct,zct; stage2v(U,scn,zcn,sct,zct);
  {
    float cnv=((float)(tid-128)-zcn)*scn;
    float ct=fminf(fmaxf(cnv,-1.f),1.f);
    lct[tid]=fqv(ct,sct,zct);
  }
  float zfc128=zfc+128.0f,zic128=zic+128.0f;
  __syncthreads();
  float mn=3.4e38f,mx=-3.4e38f;
  int t=blockIdx.x*256+tid,stride=gridDim.x*256;
  const uint2* qf2=(const uint2*)qfcic;
  const unsigned* qop=(const unsigned*)qo;
  unsigned* qcp=(unsigned*)qcn;
  for(int e=t;e<NE/4;e+=stride){
    uint2 u=qf2[e]; unsigned uo=qop[e];
    unsigned opk=0;
    #pragma unroll
    for(int j=0;j<4;j++){
      unsigned pk=((j<2)?(u.x>>(16*j)):(u.y>>(16*(j-2))))&0xffffu;
      float fcv=((float)(pk&255)-zfc128)*sfc;
      float icv=((float)(pk>>8)-zic128)*sic;
      float cn=fcv+icv;
      float qcf=qof(cn,scn,zcn);
      int qb=(int)qcf+128;
      opk|=(unsigned)qb<<(8*j);
      float hr=lao[(uo>>(8*j))&255]*lct[qb];
      mn=fminf(mn,hr);mx=fmaxf(mx,hr);
    }
    qcp[e]=opk;
  }
  int w=tid>>6,l=tid&63;
  wred(mn,mx);
  if(l==0){red[w]=mn;red[4+w]=mx;}
  __syncthreads();
  if(tid==0){
    float a=fminf(fminf(red[0],red[1]),fminf(red[2],red[3]));
    float b=fmaxf(fmaxf(red[4],red[5]),fmaxf(red[6],red[7]));
    atomicMin(&U[20],fenc(a));atomicMax(&U[21],fenc(b));
  }
}

// final outputs: h and c from codes + LUTs (scales from U)
__global__ __launch_bounds__(256) void k9_out(const uchar_t* __restrict__ qo,
    const uchar_t* __restrict__ qcn,const unsigned* __restrict__ U,
    float* __restrict__ hout,float* __restrict__ cout){
  __shared__ float lao[256],lct[256];
  int tid=threadIdx.x;
  {
    float s1,z1,s2,z2; stage0(U,2,s1,z1,s2,z2);
    lao[tid]=lut_entry(tid,2,s1,z1,s2,z2);
  }
  float scn,zcn,sct,zct; stage2v(U,scn,zcn,sct,zct);
  {
    float cnv=((float)(tid-128)-zcn)*scn;
    float ct=fminf(fmaxf(cnv,-1.f),1.f);
    lct[tid]=fqv(ct,sct,zct);
  }
  float shn,zhn; obs(fdec(U[20]),fdec(U[21]),shn,zhn);
  float zcn128=zcn+128.0f;
  __syncthreads();
  int t=blockIdx.x*256+tid,stride=gridDim.x*256;
  const unsigned* op=(const unsigned*)qo;
  const unsigned* cp=(const unsigned*)qcn;
  for(int e=t;e<NE/4;e+=stride){
    unsigned uo=op[e],uc=cp[e];
    float4 hv,cv;
    float* ph=&hv.x;float* pc=&cv.x;
    #pragma unroll
    for(int j=0;j<4;j++){
      int qoj=(uo>>(8*j))&255,qcj=(uc>>(8*j))&255;
      float cnv=((float)qcj-zcn128)*scn;
      float hr=lao[qoj]*lct[qcj];
      float qh=qof(hr,shn,zhn);
      ph[j]=(qh-zhn)*shn;
      pc[j]=cnv;
    }
    ((float4*)hout)[e]=hv;
    ((float4*)cout)[e]=cv;
  }
}

extern "C" void kernel_launch(void* const* d_in,const int* in_sizes,int n_in,
                              void* d_out,int out_size,void* d_ws,size_t ws_size,
                              hipStream_t stream){
  (void)in_sizes;(void)n_in;(void)out_size;(void)ws_size;
  const float* x  =(const float*)d_in[0];
  const float* h  =(const float*)d_in[1];
  const float* c  =(const float*)d_in[2];
  const float* Wi =(const float*)d_in[3];  const float* bi =(const float*)d_in[4];
  const float* Wf =(const float*)d_in[5];  const float* bfv=(const float*)d_in[6];
  const float* Wo =(const float*)d_in[7];  const float* bo =(const float*)d_in[8];
  const float* Wcg=(const float*)d_in[9];  const float* bcg=(const float*)d_in[10];

  char* ws=(char*)d_ws;
  unsigned* U =(unsigned*)ws;                 // 128 B
  float* S    =(float*)(ws+128);              // 256 B
  float* bq   =(float*)(ws+512);              // 1 KB
  ushort_t* LUTcx=(ushort_t*)(ws+1536);       // 1 KB cat-code LUTs (x,h)
  ushort_t* Wc=(ushort_t*)(ws+4096);          // 64 KB centered-bf16 weights
  uchar_t* qc =(uchar_t*)(ws+(1<<20));        // 32 MB c codes (biased)
  uchar_t* qo =qc +(size_t)NE;                // 32 MB o-gate codes (biased)
  uchar_t* qcn=qo +(size_t)NE;                // 32 MB c_next codes (biased)
  // d_out reuse: h-half = catc scratch (g0/g1), then qfcic (e2/e3), then h_out.
  //              c-half = qpack scratch (g1/e2), then c_out (k9).
  ushort_t* catc=(ushort_t*)d_out;
  unsigned* qpack=(unsigned*)((float*)d_out+NE);
  ushort_t* qfcic=(ushort_t*)d_out;
  float* h_out=(float*)d_out;
  float* c_out=(float*)d_out+NE;

  k0_init<<<1,64,0,stream>>>(U);
  k1_minmax<<<2048,256,0,stream>>>(x,h,c,U);
  k2_prep<<<1,256,0,stream>>>(Wi,bi,Wf,bfv,Wo,bo,Wcg,bcg,U,S,Wc,bq,LUTcx);
  k3_quant<<<4096,256,0,stream>>>(x,h,c,S,LUTcx,catc,qc);
  g0_minmax<<<4096,256,0,stream>>>(catc,Wc,S,bq,U);
  g1_codes<<<2048,256,0,stream>>>(catc,Wc,S,bq,qc,U,qpack,qo);
  e2_cn<<<4096,256,0,stream>>>(qpack,S,U,qfcic);
  e3_hmm<<<4096,256,0,stream>>>(qfcic,qo,U,qcn);
  k9_out<<<4096,256,0,stream>>>(qo,qcn,U,h_out,c_out);
}

// Round 4
// 1301.448 us; speedup vs baseline: 1.2412x; 1.2412x over previous
//
#include <hip/hip_runtime.h>
#include <stdint.h>

#define NE    33554432   // 16384*32*64  elements of each (B,W,64) tensor
#define MROWS 524288     // B*W rows of the cat matrix

typedef __attribute__((ext_vector_type(8))) short short8;
typedef __attribute__((ext_vector_type(4))) float f32x4;
typedef unsigned short ushort_t;
typedef unsigned char uchar_t;

// ---------- helpers ----------
__device__ __forceinline__ unsigned fenc(float f){
  unsigned u=__float_as_uint(f); return (u&0x80000000u)?~u:(u|0x80000000u);
}
__device__ __forceinline__ float fdec(unsigned u){
  return __uint_as_float((u&0x80000000u)?(u&0x7fffffffu):~u);
}
__device__ __forceinline__ void obs(float mn,float mx,float&s,float&zp){
  mn=fminf(mn,0.f); mx=fmaxf(mx,0.f);
  s=fmaxf((mx-mn)/255.0f,1e-8f);
  zp=fminf(fmaxf(rintf(-128.0f-mn/s),-128.f),127.f);
}
__device__ __forceinline__ float qof(float x,float s,float zp){   // quantized code (as float)
  return fminf(fmaxf(rintf(x/s)+zp,-128.f),127.f);
}
__device__ __forceinline__ float fqv(float x,float s,float zp){   // dequantized value
  return (qof(x,s,zp)-zp)*s;
}
__device__ __forceinline__ void wred(float&mn,float&mx){
  #pragma unroll
  for(int o=32;o;o>>=1){mn=fminf(mn,__shfl_xor(mn,o));mx=fmaxf(mx,__shfl_xor(mx,o));}
}
// derive gate-g stage-0 scales from U (identical math to old k_post stage 0)
__device__ __forceinline__ void stage0(const unsigned* U,int g,float&s1,float&z1,float&s2,float&z2){
  float mn=fdec(U[6+2*g]),mx=fdec(U[7+2*g]);
  obs(mn,mx,s1,z1);
  float gmn=fqv(mn,s1,z1),gmx=fqv(mx,s1,z1);
  float amn,amx;
  if(g==3){amn=fminf(fmaxf(gmn,-1.f),1.f);amx=fminf(fmaxf(gmx,-1.f),1.f);}
  else{amn=fminf(fmaxf(gmn/6.0f+0.5f,0.f),1.f);amx=fminf(fmaxf(gmx/6.0f+0.5f,0.f),1.f);}
  obs(amn,amx,s2,z2);
}
__device__ __forceinline__ float lut_entry(int t,int g,float s1,float z1,float s2,float z2){
  float g1=((float)(t-128)-z1)*s1;
  float a=(g==3)?fminf(fmaxf(g1,-1.f),1.f):fminf(fmaxf(g1/6.0f+0.5f,0.f),1.f);
  return fqv(a,s2,z2);
}
// derive cn/ct scales from U (identical math to old k_post stage 2)
__device__ __forceinline__ void stage2v(const unsigned* U,float&scn,float&zcn,float&sct,float&zct){
  float mn=fdec(U[18]),mx=fdec(U[19]);
  obs(mn,mx,scn,zcn);
  float tmn=fminf(fmaxf(fqv(mn,scn,zcn),-1.f),1.f);
  float tmx=fminf(fmaxf(fqv(mx,scn,zcn),-1.f),1.f);
  obs(tmn,tmx,sct,zct);
}

// U layout: 0,1 x | 2,3 h | 4,5 c | 6..13 gates(i,f,o,cg) | 14,15 fc | 16,17 ic | 18,19 cn | 20,21 hn
// S layout: 0-5 sx,zx,sh,zh,sc,zc | 6,7 scat,zcat | 8-15 sW[g],zW[g]

__global__ void k0_init(unsigned* U){
  int t=threadIdx.x;
  if(t<11){U[2*t]=0xFFFFFFFFu;U[2*t+1]=0u;}
}

__global__ __launch_bounds__(256) void k1_minmax(const float* __restrict__ x,
    const float* __restrict__ h,const float* __restrict__ c,unsigned* U){
  __shared__ float red[8];
  int t=blockIdx.x*256+threadIdx.x, stride=gridDim.x*256;
  int w=threadIdx.x>>6,l=threadIdx.x&63;
  const float4* ps[3]={(const float4*)x,(const float4*)h,(const float4*)c};
  for(int q=0;q<3;q++){
    float mn=3.4e38f,mx=-3.4e38f;
    const float4* p=ps[q];
    for(int e=t;e<NE/4;e+=4*stride){      // NE/4 divisible by 4*stride for grid 2048
      float4 a=p[e],b=p[e+stride],c4=p[e+2*stride],d=p[e+3*stride];
      mn=fminf(mn,fminf(fminf(a.x,a.y),fminf(a.z,a.w)));
      mx=fmaxf(mx,fmaxf(fmaxf(a.x,a.y),fmaxf(a.z,a.w)));
      mn=fminf(mn,fminf(fminf(b.x,b.y),fminf(b.z,b.w)));
      mx=fmaxf(mx,fmaxf(fmaxf(b.x,b.y),fmaxf(b.z,b.w)));
      mn=fminf(mn,fminf(fminf(c4.x,c4.y),fminf(c4.z,c4.w)));
      mx=fmaxf(mx,fmaxf(fmaxf(c4.x,c4.y),fmaxf(c4.z,c4.w)));
      mn=fminf(mn,fminf(fminf(d.x,d.y),fminf(d.z,d.w)));
      mx=fmaxf(mx,fmaxf(fmaxf(d.x,d.y),fmaxf(d.z,d.w)));
    }
    wred(mn,mx);
    if(l==0){red[w]=mn;red[4+w]=mx;}
    __syncthreads();
    if(threadIdx.x==0){
      float bmn=fminf(fminf(red[0],red[1]),fminf(red[2],red[3]));
      float bmx=fmaxf(fmaxf(red[4],red[5]),fmaxf(red[6],red[7]));
      atomicMin(&U[2*q],fenc(bmn)); atomicMax(&U[2*q+1],fenc(bmx));
    }
    __syncthreads();
  }
}

// scalars for x/h/c/cat + cat LUTs + per-gate weight/bias quantization (single block)
__global__ __launch_bounds__(256) void k2_prep(const float* Wi,const float* bi,
    const float* Wf,const float* bfv,const float* Wo,const float* bo,
    const float* Wcg,const float* bcg,
    const unsigned* U,float* S,ushort_t* Wc,float* bq,ushort_t* LUTcx){
  __shared__ float smn[256],smx[256],sP[4],sS[8];
  int t=threadIdx.x;
  if(t==0){
    float xmn=fdec(U[0]),xmx=fdec(U[1]),hmn=fdec(U[2]),hmx=fdec(U[3]),cmn=fdec(U[4]),cmx=fdec(U[5]);
    float sx,zx,sh,zh,sc,zc;
    obs(xmn,xmx,sx,zx);obs(hmn,hmx,sh,zh);obs(cmn,cmx,sc,zc);
    S[0]=sx;S[1]=zx;S[2]=sh;S[3]=zh;S[4]=sc;S[5]=zc;
    sS[0]=sx;sS[1]=zx;sS[2]=sh;sS[3]=zh;sS[4]=sc;sS[5]=zc;
    float cmn2=fminf(fqv(xmn,sx,zx),fqv(hmn,sh,zh));
    float cmx2=fmaxf(fqv(xmx,sx,zx),fqv(hmx,sh,zh));
    float scat,zcat;obs(cmn2,cmx2,scat,zcat);S[6]=scat;S[7]=zcat;
    sS[6]=scat;sS[7]=zcat;
  }
  __syncthreads();
  { // exact cat-code LUTs: inner code -> centered bf16 cat code
    float sx=sS[0],zx=sS[1],sh=sS[2],zh=sS[3],scat=sS[6],zcat=sS[7];
    float cx=qof(((float)(t-128)-zx)*sx,scat,zcat)-zcat;
    float ch=qof(((float)(t-128)-zh)*sh,scat,zcat)-zcat;
    LUTcx[t]    =(ushort_t)(__float_as_uint(cx)>>16);
    LUTcx[256+t]=(ushort_t)(__float_as_uint(ch)>>16);
  }
  const float* Wp[4]={Wi,Wf,Wo,Wcg};
  const float* bp[4]={bi,bfv,bo,bcg};
  for(int g=0;g<4;g++){
    float mn=3.4e38f,mx=-3.4e38f;
    for(int i=t;i<8192;i+=256){float v=Wp[g][i];mn=fminf(mn,v);mx=fmaxf(mx,v);}
    smn[t]=mn;smx[t]=mx;__syncthreads();
    for(int ss=128;ss;ss>>=1){
      if(t<ss){smn[t]=fminf(smn[t],smn[t+ss]);smx[t]=fmaxf(smx[t],smx[t+ss]);}
      __syncthreads();
    }
    if(t==0){
      float s_,z_;obs(smn[0],smx[0],s_,z_);
      S[8+2*g]=s_;S[9+2*g]=z_;sP[0]=s_;sP[1]=z_;
      float bmn=3.4e38f,bmx=-3.4e38f;
      for(int i=0;i<64;i++){float v=bp[g][i];bmn=fminf(bmn,v);bmx=fmaxf(bmx,v);}
      float sb,zb;obs(bmn,bmx,sb,zb);sP[2]=sb;sP[3]=zb;
    }
    __syncthreads();
    float s_=sP[0],z_=sP[1],sb=sP[2],zb=sP[3];
    for(int i=t;i<8192;i+=256){
      float cv=qof(Wp[g][i],s_,z_)-z_;                 // centered integer, exact in bf16
      Wc[g*8192+i]=(ushort_t)(__float_as_uint(cv)>>16);
    }
    if(t<64) bq[g*64+t]=fqv(bp[g][t],sb,zb);
    __syncthreads();
  }
}

// quantize: cat -> centered bf16 via LUT (1 divide/elem), c -> biased int8 codes
__global__ __launch_bounds__(256) void k3_quant(const float* __restrict__ x,
    const float* __restrict__ h,const float* __restrict__ c,
    const float* __restrict__ S,const ushort_t* __restrict__ LUTcx,
    ushort_t* __restrict__ catc,uchar_t* __restrict__ qc){
  __shared__ ushort_t lcx[512];
  int tid=threadIdx.x;
  for(int i=tid;i<512;i+=256) lcx[i]=LUTcx[i];
  float sx=S[0],zx=S[1],sh=S[2],zh=S[3],sc=S[4],zc=S[5];
  __syncthreads();
  int t=blockIdx.x*256+tid, stride=gridDim.x*256;
  const float4* xp=(const float4*)x; const float4* hp=(const float4*)h;
  for(int e=t;e<MROWS*32;e+=stride){      // 32 float4 per 128-wide row
    int row=e>>5,k4=e&31;
    float4 v; float s1,z1; int off;
    if(k4<16){v=xp[row*16+k4];s1=sx;z1=zx;off=0;}
    else     {v=hp[row*16+(k4-16)];s1=sh;z1=zh;off=256;}
    int q0=(int)qof(v.x,s1,z1)+128;
    int q1=(int)qof(v.y,s1,z1)+128;
    int q2=(int)qof(v.z,s1,z1)+128;
    int q3=(int)qof(v.w,s1,z1)+128;
    uint2 o;
    o.x=(unsigned)lcx[off+q0]|((unsigned)lcx[off+q1]<<16);
    o.y=(unsigned)lcx[off+q2]|((unsigned)lcx[off+q3]<<16);
    ((uint2*)catc)[e]=o;
  }
  const float4* cp=(const float4*)c;
  unsigned* qcp=(unsigned*)qc;
  for(int e=t;e<NE/4;e+=stride){
    float4 v=cp[e];
    int q0=(int)qof(v.x,sc,zc)+128,q1=(int)qof(v.y,sc,zc)+128;
    int q2=(int)qof(v.z,sc,zc)+128,q3=(int)qof(v.w,sc,zc)+128;
    qcp[e]=(unsigned)q0|((unsigned)q1<<8)|((unsigned)q2<<16)|((unsigned)q3<<24);
  }
}

// GEMM pass A: gate pre-act minmax. Round-1 proven structure: grid 1024, 8 groups/block,
// mt fully unrolled (16 A-loads in flight), plain launch_bounds (no VGPR strangle).
// Per-nt acc minmax with affine folded after (exact: v=sgp*acc+bqr monotone, sgp>0).
__global__ __launch_bounds__(256) void g0_minmax(const ushort_t* __restrict__ catc,
    const ushort_t* __restrict__ Wc,const float* __restrict__ S,
    const float* __restrict__ bq,unsigned* U){
  int tid=threadIdx.x,w=tid>>6,l=tid&63,l15=l&15,lq=l>>4;
  float sgp=S[6]*S[8+2*w];                   // s_cat * s_w[gate]
  short8 bf[4][4];
  #pragma unroll
  for(int nt=0;nt<4;nt++)
    #pragma unroll
    for(int ks=0;ks<4;ks++)
      bf[nt][ks]=*(const short8*)(Wc+w*8192+(nt*16+l15)*128+ks*32+lq*8);
  float bqr[4];
  #pragma unroll
  for(int nt=0;nt<4;nt++) bqr[nt]=bq[w*64+nt*16+l15];
  float mnA[4],mxA[4];
  #pragma unroll
  for(int nt=0;nt<4;nt++){mnA[nt]=3.4e38f;mxA[nt]=-3.4e38f;}
  for(int gi=0;gi<8;gi++){
    int rowbase=(blockIdx.x*8+gi)*64;
    #pragma unroll
    for(int mt=0;mt<4;mt++){
      const ushort_t* arow=catc+(size_t)(rowbase+mt*16+l15)*128;
      short8 af[4];
      #pragma unroll
      for(int ks=0;ks<4;ks++) af[ks]=*(const short8*)(arow+ks*32+lq*8);
      f32x4 acc[4];
      #pragma unroll
      for(int nt=0;nt<4;nt++) acc[nt]=(f32x4){0.f,0.f,0.f,0.f};
      #pragma unroll
      for(int ks=0;ks<4;ks++)
        #pragma unroll
        for(int nt=0;nt<4;nt++)
          acc[nt]=__builtin_amdgcn_mfma_f32_16x16x32_bf16(af[ks],bf[nt][ks],acc[nt],0,0,0);
      #pragma unroll
      for(int nt=0;nt<4;nt++)
        #pragma unroll
        for(int r=0;r<4;r++){
          mnA[nt]=fminf(mnA[nt],acc[nt][r]);
          mxA[nt]=fmaxf(mxA[nt],acc[nt][r]);
        }
    }
  }
  float mn=3.4e38f,mx=-3.4e38f;
  #pragma unroll
  for(int nt=0;nt<4;nt++){
    mn=fminf(mn,sgp*mnA[nt]+bqr[nt]);
    mx=fmaxf(mx,sgp*mxA[nt]+bqr[nt]);
  }
  wred(mn,mx);
  if(l==0){atomicMin(&U[6+2*w],fenc(mn));atomicMax(&U[7+2*w],fenc(mx));}
}

// GEMM pass B: quantize pre-acts to codes once, store packed codes, fc/ic minmax via LUT.
// 32-row exchange tile (padded to 66 -> <=2-way write conflicts) ~38KB LDS.
// launch_bounds(256,2): leaves the allocator free; ~88 VGPR + 38KB LDS -> 4 blocks/CU.
__global__ __launch_bounds__(256,2) void g1_codes(const ushort_t* __restrict__ catc,
    const ushort_t* __restrict__ Wc,const float* __restrict__ S,
    const float* __restrict__ bq,const uchar_t* __restrict__ qc,
    unsigned* U,unsigned* __restrict__ qpack,uchar_t* __restrict__ qo){
  __shared__ float ldsq[4][32][66];
  __shared__ float lut[1024];
  __shared__ float red[16];
  int tid=threadIdx.x,w=tid>>6,l=tid&63,l15=l&15,lq=l>>4;
  float sg1,zg1;
  #pragma unroll
  for(int g=0;g<4;g++){
    float s1,z1,s2,z2; stage0(U,g,s1,z1,s2,z2);
    if(g==w){sg1=s1;zg1=z1;}
    lut[g*256+tid]=lut_entry(tid,g,s1,z1,s2,z2);
  }
  float sgp=S[6]*S[8+2*w];
  float sc=S[4],zc128=S[5]+128.0f;
  short8 bf[4][4];
  #pragma unroll
  for(int nt=0;nt<4;nt++)
    #pragma unroll
    for(int ks=0;ks<4;ks++)
      bf[nt][ks]=*(const short8*)(Wc+w*8192+(nt*16+l15)*128+ks*32+lq*8);
  float bqr[4];
  #pragma unroll
  for(int nt=0;nt<4;nt++) bqr[nt]=bq[w*64+nt*16+l15];
  __syncthreads();
  float fmn=3.4e38f,fmx=-3.4e38f,imn=3.4e38f,imx=-3.4e38f;
  for(int gi=0;gi<4;gi++){
    int grp=blockIdx.x*4+gi;
    #pragma unroll
    for(int half=0;half<2;half++){
      #pragma unroll
      for(int mt2=0;mt2<2;mt2++){
        int mt=half*2+mt2;
        const ushort_t* arow=catc+(size_t)(grp*64+mt*16+l15)*128;
        short8 af[4];
        #pragma unroll
        for(int ks=0;ks<4;ks++) af[ks]=*(const short8*)(arow+ks*32+lq*8);
        f32x4 acc[4];
        #pragma unroll
        for(int nt=0;nt<4;nt++) acc[nt]=(f32x4){0.f,0.f,0.f,0.f};
        #pragma unroll
        for(int ks=0;ks<4;ks++)
          #pragma unroll
          for(int nt=0;nt<4;nt++)
            acc[nt]=__builtin_amdgcn_mfma_f32_16x16x32_bf16(af[ks],bf[nt][ks],acc[nt],0,0,0);
        #pragma unroll
        for(int nt=0;nt<4;nt++)
          #pragma unroll
          for(int r=0;r<4;r++)
            ldsq[w][mt2*16+lq*4+r][nt*16+l15]=qof(sgp*acc[nt][r]+bqr[nt],sg1,zg1);
      }
      __syncthreads();
      #pragma unroll
      for(int it=0;it<2;it++){
        int e4=(tid+it*256)<<2;                 // 0..2044 within half-tile
        int gidx=grp*4096+half*2048+e4;
        unsigned qcw=*(const unsigned*)(qc+gidx);
        uint4 qp; unsigned qob=0;
        #pragma unroll
        for(int j=0;j<4;j++){
          int row=(e4+j)>>6, col=(e4+j)&63;
          int q0=(int)ldsq[0][row][col]+128;    // i
          int q1=(int)ldsq[1][row][col]+128;    // f
          int q2=(int)ldsq[2][row][col]+128;    // o
          int q3=(int)ldsq[3][row][col]+128;    // cg
          int qcb=(int)((qcw>>(8*j))&255);
          ((unsigned*)&qp)[j]=(unsigned)q0|((unsigned)q1<<8)|((unsigned)q3<<16)|((unsigned)qcb<<24);
          qob|=(unsigned)q2<<(8*j);
          float avi=lut[q0],avf=lut[256+q1],avcg=lut[768+q3];
          float cv=((float)qcb-zc128)*sc;
          float fc=avf*cv,ic=avi*avcg;
          fmn=fminf(fmn,fc);fmx=fmaxf(fmx,fc);
          imn=fminf(imn,ic);imx=fmaxf(imx,ic);
        }
        *(uint4*)(qpack+gidx)=qp;
        *(unsigned*)(qo+gidx)=qob;
      }
      __syncthreads();
    }
  }
  wred(fmn,fmx);wred(imn,imx);
  if(l==0){red[w]=fmn;red[4+w]=fmx;red[8+w]=imn;red[12+w]=imx;}
  __syncthreads();
  if(tid==0){
    float a=fminf(fminf(red[0],red[1]),fminf(red[2],red[3]));
    float b=fmaxf(fmaxf(red[4],red[5]),fmaxf(red[6],red[7]));
    atomicMin(&U[14],fenc(a));atomicMax(&U[15],fenc(b));
    a=fminf(fminf(red[8],red[9]),fminf(red[10],red[11]));
    b=fmaxf(fmaxf(red[12],red[13]),fmaxf(red[14],red[15]));
    atomicMin(&U[16],fenc(a));atomicMax(&U[17],fenc(b));
  }
}

// elementwise: cn minmax + fc/ic codes (x4 vectorized, scales derived from U)
__global__ __launch_bounds__(256) void e2_cn(const unsigned* __restrict__ qpack,
    const float* __restrict__ S,unsigned* U,ushort_t* __restrict__ qfcic){
  __shared__ float lut[1024];
  __shared__ float red[8];
  int tid=threadIdx.x;
  #pragma unroll
  for(int g=0;g<4;g++){
    float s1,z1,s2,z2; stage0(U,g,s1,z1,s2,z2);
    lut[g*256+tid]=lut_entry(tid,g,s1,z1,s2,z2);
  }
  float sfc,zfc,sic,zic;
  obs(fdec(U[14]),fdec(U[15]),sfc,zfc);
  obs(fdec(U[16]),fdec(U[17]),sic,zic);
  float sc=S[4],zc128=S[5]+128.0f;
  __syncthreads();
  float mn=3.4e38f,mx=-3.4e38f;
  int t=blockIdx.x*256+tid,stride=gridDim.x*256;
  const uint4* qp4=(const uint4*)qpack;
  uint2* qf2=(uint2*)qfcic;
  for(int e=t;e<NE/4;e+=stride){
    uint4 u4=qp4[e];
    unsigned lo=0,hi=0;
    #pragma unroll
    for(int j=0;j<4;j++){
      unsigned u=((const unsigned*)&u4)[j];
      int q0=u&255,q1=(u>>8)&255,q3=(u>>16)&255,qcb=u>>24;
      float avi=lut[q0],avf=lut[256+q1],avcg=lut[768+q3];
      float cv=((float)qcb-zc128)*sc;
      float fc=avf*cv,ic=avi*avcg;
      float qfc=qof(fc,sfc,zfc),qic=qof(ic,sic,zic);
      float cn=(qfc-zfc)*sfc+(qic-zic)*sic;
      mn=fminf(mn,cn);mx=fmaxf(mx,cn);
      unsigned pk=(unsigned)((int)qfc+128)|((unsigned)((int)qic+128)<<8);
      if(j<2) lo|=pk<<(16*j); else hi|=pk<<(16*(j-2));
    }
    uint2 o; o.x=lo; o.y=hi;
    qf2[e]=o;
  }
  int w=tid>>6,l=tid&63;
  wred(mn,mx);
  if(l==0){red[w]=mn;red[4+w]=mx;}
  __syncthreads();
  if(tid==0){
    float a=fminf(fminf(red[0],red[1]),fminf(red[2],red[3]));
    float b=fmaxf(fmaxf(red[4],red[5]),fmaxf(red[6],red[7]));
    atomicMin(&U[18],fenc(a));atomicMax(&U[19],fenc(b));
  }
}

// elementwise: c_next codes + h_raw minmax (x4 vectorized, scales/LUTs from U)
__global__ __launch_bounds__(256) void e3_hmm(const ushort_t* __restrict__ qfcic,
    const uchar_t* __restrict__ qo,unsigned* U,uchar_t* __restrict__ qcn){
  __shared__ float lao[256],lct[256];
  __shared__ float red[8];
  int tid=threadIdx.x;
  {
    float s1,z1,s2,z2; stage0(U,2,s1,z1,s2,z2);
    lao[tid]=lut_entry(tid,2,s1,z1,s2,z2);
  }
  float sfc,zfc,sic,zic;
  obs(fdec(U[14]),fdec(U[15]),sfc,zfc);
  obs(fdec(U[16]),fdec(U[17]),sic,zic);
  float scn,zcn,sct,zct; stage2v(U,scn,zcn,sct,zct);
  {
    float cnv=((float)(tid-128)-zcn)*scn;
    float ct=fminf(fmaxf(cnv,-1.f),1.f);
    lct[tid]=fqv(ct,sct,zct);
  }
  float zfc128=zfc+128.0f,zic128=zic+128.0f;
  __syncthreads();
  float mn=3.4e38f,mx=-3.4e38f;
  int t=blockIdx.x*256+tid,stride=gridDim.x*256;
  const uint2* qf2=(const uint2*)qfcic;
  const unsigned* qop=(const unsigned*)qo;
  unsigned* qcp=(unsigned*)qcn;
  for(int e=t;e<NE/4;e+=stride){
    uint2 u=qf2[e]; unsigned uo=qop[e];
    unsigned opk=0;
    #pragma unroll
    for(int j=0;j<4;j++){
      unsigned pk=((j<2)?(u.x>>(16*j)):(u.y>>(16*(j-2))))&0xffffu;
      float fcv=((float)(pk&255)-zfc128)*sfc;
      float icv=((float)(pk>>8)-zic128)*sic;
      float cn=fcv+icv;
      float qcf=qof(cn,scn,zcn);
      int qb=(int)qcf+128;
      opk|=(unsigned)qb<<(8*j);
      float hr=lao[(uo>>(8*j))&255]*lct[qb];
      mn=fminf(mn,hr);mx=fmaxf(mx,hr);
    }
    qcp[e]=opk;
  }
  int w=tid>>6,l=tid&63;
  wred(mn,mx);
  if(l==0){red[w]=mn;red[4+w]=mx;}
  __syncthreads();
  if(tid==0){
    float a=fminf(fminf(red[0],red[1]),fminf(red[2],red[3]));
    float b=fmaxf(fmaxf(red[4],red[5]),fmaxf(red[6],red[7]));
    atomicMin(&U[20],fenc(a));atomicMax(&U[21],fenc(b));
  }
}

// final outputs: h and c from codes + LUTs (scales from U)
__global__ __launch_bounds__(256) void k9_out(const uchar_t* __restrict__ qo,
    const uchar_t* __restrict__ qcn,const unsigned* __restrict__ U,
    float* __restrict__ hout,float* __restrict__ cout){
  __shared__ float lao[256],lct[256];
  int tid=threadIdx.x;
  {
    float s1,z1,s2,z2; stage0(U,2,s1,z1,s2,z2);
    lao[tid]=lut_entry(tid,2,s1,z1,s2,z2);
  }
  float scn,zcn,sct,zct; stage2v(U,scn,zcn,sct,zct);
  {
    float cnv=((float)(tid-128)-zcn)*scn;
    float ct=fminf(fmaxf(cnv,-1.f),1.f);
    lct[tid]=fqv(ct,sct,zct);
  }
  float shn,zhn; obs(fdec(U[20]),fdec(U[21]),shn,zhn);
  float zcn128=zcn+128.0f;
  __syncthreads();
  int t=blockIdx.x*256+tid,stride=gridDim.x*256;
  const unsigned* op=(const unsigned*)qo;
  const unsigned* cp=(const unsigned*)qcn;
  for(int e=t;e<NE/4;e+=stride){
    unsigned uo=op[e],uc=cp[e];
    float4 hv,cv;
    float* ph=&hv.x;float* pc=&cv.x;
    #pragma unroll
    for(int j=0;j<4;j++){
      int qoj=(uo>>(8*j))&255,qcj=(uc>>(8*j))&255;
      float cnv=((float)qcj-zcn128)*scn;
      float hr=lao[qoj]*lct[qcj];
      float qh=qof(hr,shn,zhn);
      ph[j]=(qh-zhn)*shn;
      pc[j]=cnv;
    }
    ((float4*)hout)[e]=hv;
    ((float4*)cout)[e]=cv;
  }
}

extern "C" void kernel_launch(void* const* d_in,const int* in_sizes,int n_in,
                              void* d_out,int out_size,void* d_ws,size_t ws_size,
                              hipStream_t stream){
  (void)in_sizes;(void)n_in;(void)out_size;(void)ws_size;
  const float* x  =(const float*)d_in[0];
  const float* h  =(const float*)d_in[1];
  const float* c  =(const float*)d_in[2];
  const float* Wi =(const float*)d_in[3];  const float* bi =(const float*)d_in[4];
  const float* Wf =(const float*)d_in[5];  const float* bfv=(const float*)d_in[6];
  const float* Wo =(const float*)d_in[7];  const float* bo =(const float*)d_in[8];
  const float* Wcg=(const float*)d_in[9];  const float* bcg=(const float*)d_in[10];

  char* ws=(char*)d_ws;
  unsigned* U =(unsigned*)ws;                 // 128 B
  float* S    =(float*)(ws+128);              // 256 B
  float* bq   =(float*)(ws+512);              // 1 KB
  ushort_t* LUTcx=(ushort_t*)(ws+1536);       // 1 KB cat-code LUTs (x,h)
  ushort_t* Wc=(ushort_t*)(ws+4096);          // 64 KB centered-bf16 weights
  uchar_t* qc =(uchar_t*)(ws+(1<<20));        // 32 MB c codes (biased)
  uchar_t* qo =qc +(size_t)NE;                // 32 MB o-gate codes (biased)
  uchar_t* qcn=qo +(size_t)NE;                // 32 MB c_next codes (biased)
  // d_out reuse: h-half = catc scratch (g0/g1), then qfcic (e2/e3), then h_out.
  //              c-half = qpack scratch (g1/e2), then c_out (k9).
  ushort_t* catc=(ushort_t*)d_out;
  unsigned* qpack=(unsigned*)((float*)d_out+NE);
  ushort_t* qfcic=(ushort_t*)d_out;
  float* h_out=(float*)d_out;
  float* c_out=(float*)d_out+NE;

  k0_init<<<1,64,0,stream>>>(U);
  k1_minmax<<<2048,256,0,stream>>>(x,h,c,U);
  k2_prep<<<1,256,0,stream>>>(Wi,bi,Wf,bfv,Wo,bo,Wcg,bcg,U,S,Wc,bq,LUTcx);
  k3_quant<<<4096,256,0,stream>>>(x,h,c,S,LUTcx,catc,qc);
  g0_minmax<<<1024,256,0,stream>>>(catc,Wc,S,bq,U);
  g1_codes<<<2048,256,0,stream>>>(catc,Wc,S,bq,qc,U,qpack,qo);
  e2_cn<<<4096,256,0,stream>>>(qpack,S,U,qfcic);
  e3_hmm<<<4096,256,0,stream>>>(qfcic,qo,U,qcn);
  k9_out<<<4096,256,0,stream>>>(qo,qcn,U,h_out,c_out);
}

// Round 5
// 1245.016 us; speedup vs baseline: 1.2974x; 1.0453x over previous
//
#include <hip/hip_runtime.h>
#include <stdint.h>

#define NE    33554432   // 16384*32*64  elements of each (B,W,64) tensor
#define MROWS 524288     // B*W rows of the cat matrix

typedef __attribute__((ext_vector_type(8))) short short8;
typedef __attribute__((ext_vector_type(4))) float f32x4;
typedef unsigned short ushort_t;
typedef unsigned char uchar_t;

// ---------- helpers ----------
__device__ __forceinline__ unsigned fenc(float f){
  unsigned u=__float_as_uint(f); return (u&0x80000000u)?~u:(u|0x80000000u);
}
__device__ __forceinline__ float fdec(unsigned u){
  return __uint_as_float((u&0x80000000u)?(u&0x7fffffffu):~u);
}
__device__ __forceinline__ void obs(float mn,float mx,float&s,float&zp){
  mn=fminf(mn,0.f); mx=fmaxf(mx,0.f);
  s=fmaxf((mx-mn)/255.0f,1e-8f);
  zp=fminf(fmaxf(rintf(-128.0f-mn/s),-128.f),127.f);
}
__device__ __forceinline__ float qof(float x,float s,float zp){   // quantized code (as float)
  return fminf(fmaxf(rintf(x/s)+zp,-128.f),127.f);
}
__device__ __forceinline__ float fqv(float x,float s,float zp){   // dequantized value
  return (qof(x,s,zp)-zp)*s;
}
__device__ __forceinline__ void wred(float&mn,float&mx){
  #pragma unroll
  for(int o=32;o;o>>=1){mn=fminf(mn,__shfl_xor(mn,o));mx=fmaxf(mx,__shfl_xor(mx,o));}
}
__device__ __forceinline__ void mm4(const float4&v,float&mn,float&mx){
  mn=fminf(mn,fminf(fminf(v.x,v.y),fminf(v.z,v.w)));
  mx=fmaxf(mx,fmaxf(fmaxf(v.x,v.y),fmaxf(v.z,v.w)));
}
// derive gate-g stage-0 scales from U (identical math to old k_post stage 0)
__device__ __forceinline__ void stage0(const unsigned* U,int g,float&s1,float&z1,float&s2,float&z2){
  float mn=fdec(U[6+2*g]),mx=fdec(U[7+2*g]);
  obs(mn,mx,s1,z1);
  float gmn=fqv(mn,s1,z1),gmx=fqv(mx,s1,z1);
  float amn,amx;
  if(g==3){amn=fminf(fmaxf(gmn,-1.f),1.f);amx=fminf(fmaxf(gmx,-1.f),1.f);}
  else{amn=fminf(fmaxf(gmn/6.0f+0.5f,0.f),1.f);amx=fminf(fmaxf(gmx/6.0f+0.5f,0.f),1.f);}
  obs(amn,amx,s2,z2);
}
__device__ __forceinline__ float lut_entry(int t,int g,float s1,float z1,float s2,float z2){
  float g1=((float)(t-128)-z1)*s1;
  float a=(g==3)?fminf(fmaxf(g1,-1.f),1.f):fminf(fmaxf(g1/6.0f+0.5f,0.f),1.f);
  return fqv(a,s2,z2);
}
// derive cn/ct scales from U (identical math to old k_post stage 2)
__device__ __forceinline__ void stage2v(const unsigned* U,float&scn,float&zcn,float&sct,float&zct){
  float mn=fdec(U[18]),mx=fdec(U[19]);
  obs(mn,mx,scn,zcn);
  float tmn=fminf(fmaxf(fqv(mn,scn,zcn),-1.f),1.f);
  float tmx=fminf(fmaxf(fqv(mx,scn,zcn),-1.f),1.f);
  obs(tmn,tmx,sct,zct);
}

// U layout: 0,1 x | 2,3 h | 4,5 c | 6..13 gates(i,f,o,cg) | 14,15 fc | 16,17 ic | 18,19 cn | 20,21 hn
// S layout: 0-5 sx,zx,sh,zh,sc,zc | 6,7 scat,zcat | 8-15 sW[g],zW[g]

__global__ void k0_init(unsigned* U){
  int t=threadIdx.x;
  if(t<11){U[2*t]=0xFFFFFFFFu;U[2*t+1]=0u;}
}

// fused 3-tensor minmax: 6 float4 loads in flight, one reduction epilogue
__global__ __launch_bounds__(256) void k1_minmax(const float* __restrict__ x,
    const float* __restrict__ h,const float* __restrict__ c,unsigned* U){
  __shared__ float red[24];
  int t=blockIdx.x*256+threadIdx.x, stride=gridDim.x*256;
  int w=threadIdx.x>>6,l=threadIdx.x&63;
  const float4* xp=(const float4*)x;
  const float4* hp=(const float4*)h;
  const float4* cp=(const float4*)c;
  float xmn=3.4e38f,xmx=-3.4e38f,hmn=3.4e38f,hmx=-3.4e38f,cmn=3.4e38f,cmx=-3.4e38f;
  for(int e=t;e<NE/4;e+=2*stride){          // grid 2048 -> exactly 8 iterations
    float4 a0=xp[e],a1=xp[e+stride];
    float4 b0=hp[e],b1=hp[e+stride];
    float4 d0=cp[e],d1=cp[e+stride];
    mm4(a0,xmn,xmx);mm4(a1,xmn,xmx);
    mm4(b0,hmn,hmx);mm4(b1,hmn,hmx);
    mm4(d0,cmn,cmx);mm4(d1,cmn,cmx);
  }
  wred(xmn,xmx);wred(hmn,hmx);wred(cmn,cmx);
  if(l==0){
    red[w]=xmn;red[4+w]=xmx;red[8+w]=hmn;red[12+w]=hmx;red[16+w]=cmn;red[20+w]=cmx;
  }
  __syncthreads();
  if(threadIdx.x==0){
    #pragma unroll
    for(int q=0;q<3;q++){
      float bmn=fminf(fminf(red[8*q],red[8*q+1]),fminf(red[8*q+2],red[8*q+3]));
      float bmx=fmaxf(fmaxf(red[8*q+4],red[8*q+5]),fmaxf(red[8*q+6],red[8*q+7]));
      atomicMin(&U[2*q],fenc(bmn)); atomicMax(&U[2*q+1],fenc(bmx));
    }
  }
}

// scalars for x/h/c/cat + cat LUTs + per-gate weight/bias quantization (single block)
__global__ __launch_bounds__(256) void k2_prep(const float* Wi,const float* bi,
    const float* Wf,const float* bfv,const float* Wo,const float* bo,
    const float* Wcg,const float* bcg,
    const unsigned* U,float* S,ushort_t* Wc,float* bq,ushort_t* LUTcx){
  __shared__ float smn[256],smx[256],sP[4],sS[8];
  int t=threadIdx.x;
  if(t==0){
    float xmn=fdec(U[0]),xmx=fdec(U[1]),hmn=fdec(U[2]),hmx=fdec(U[3]),cmn=fdec(U[4]),cmx=fdec(U[5]);
    float sx,zx,sh,zh,sc,zc;
    obs(xmn,xmx,sx,zx);obs(hmn,hmx,sh,zh);obs(cmn,cmx,sc,zc);
    S[0]=sx;S[1]=zx;S[2]=sh;S[3]=zh;S[4]=sc;S[5]=zc;
    sS[0]=sx;sS[1]=zx;sS[2]=sh;sS[3]=zh;sS[4]=sc;sS[5]=zc;
    float cmn2=fminf(fqv(xmn,sx,zx),fqv(hmn,sh,zh));
    float cmx2=fmaxf(fqv(xmx,sx,zx),fqv(hmx,sh,zh));
    float scat,zcat;obs(cmn2,cmx2,scat,zcat);S[6]=scat;S[7]=zcat;
    sS[6]=scat;sS[7]=zcat;
  }
  __syncthreads();
  { // exact cat-code LUTs: inner code -> centered bf16 cat code
    float sx=sS[0],zx=sS[1],sh=sS[2],zh=sS[3],scat=sS[6],zcat=sS[7];
    float cx=qof(((float)(t-128)-zx)*sx,scat,zcat)-zcat;
    float ch=qof(((float)(t-128)-zh)*sh,scat,zcat)-zcat;
    LUTcx[t]    =(ushort_t)(__float_as_uint(cx)>>16);
    LUTcx[256+t]=(ushort_t)(__float_as_uint(ch)>>16);
  }
  const float* Wp[4]={Wi,Wf,Wo,Wcg};
  const float* bp[4]={bi,bfv,bo,bcg};
  for(int g=0;g<4;g++){
    float mn=3.4e38f,mx=-3.4e38f;
    for(int i=t;i<8192;i+=256){float v=Wp[g][i];mn=fminf(mn,v);mx=fmaxf(mx,v);}
    smn[t]=mn;smx[t]=mx;__syncthreads();
    for(int ss=128;ss;ss>>=1){
      if(t<ss){smn[t]=fminf(smn[t],smn[t+ss]);smx[t]=fmaxf(smx[t],smx[t+ss]);}
      __syncthreads();
    }
    if(t==0){
      float s_,z_;obs(smn[0],smx[0],s_,z_);
      S[8+2*g]=s_;S[9+2*g]=z_;sP[0]=s_;sP[1]=z_;
      float bmn=3.4e38f,bmx=-3.4e38f;
      for(int i=0;i<64;i++){float v=bp[g][i];bmn=fminf(bmn,v);bmx=fmaxf(bmx,v);}
      float sb,zb;obs(bmn,bmx,sb,zb);sP[2]=sb;sP[3]=zb;
    }
    __syncthreads();
    float s_=sP[0],z_=sP[1],sb=sP[2],zb=sP[3];
    for(int i=t;i<8192;i+=256){
      float cv=qof(Wp[g][i],s_,z_)-z_;                 // centered integer, exact in bf16
      Wc[g*8192+i]=(ushort_t)(__float_as_uint(cv)>>16);
    }
    if(t<64) bq[g*64+t]=fqv(bp[g][t],sb,zb);
    __syncthreads();
  }
}

// quantize: cat -> centered bf16 via LUT (1 divide/elem), c -> biased int8 codes
// 2-way unrolled (stride%32==0 -> unrolled pair shares the x/h branch)
__global__ __launch_bounds__(256) void k3_quant(const float* __restrict__ x,
    const float* __restrict__ h,const float* __restrict__ c,
    const float* __restrict__ S,const ushort_t* __restrict__ LUTcx,
    ushort_t* __restrict__ catc,uchar_t* __restrict__ qc){
  __shared__ ushort_t lcx[512];
  int tid=threadIdx.x;
  for(int i=tid;i<512;i+=256) lcx[i]=LUTcx[i];
  float sx=S[0],zx=S[1],sh=S[2],zh=S[3],sc=S[4],zc=S[5];
  __syncthreads();
  int t=blockIdx.x*256+tid, stride=gridDim.x*256;
  const float4* xp=(const float4*)x; const float4* hp=(const float4*)h;
  for(int e=t;e<MROWS*32;e+=2*stride){   // grid 2048 -> 16 unrolled-pair iters
    int eb=e+stride;
    int row0=e>>5,row1=eb>>5,k4=e&31;    // same k4 for both
    float4 v0,v1; float s1,z1; int off;
    if(k4<16){v0=xp[row0*16+k4];v1=xp[row1*16+k4];s1=sx;z1=zx;off=0;}
    else     {v0=hp[row0*16+(k4-16)];v1=hp[row1*16+(k4-16)];s1=sh;z1=zh;off=256;}
    int a0=(int)qof(v0.x,s1,z1)+128,a1=(int)qof(v0.y,s1,z1)+128;
    int a2=(int)qof(v0.z,s1,z1)+128,a3=(int)qof(v0.w,s1,z1)+128;
    int b0=(int)qof(v1.x,s1,z1)+128,b1=(int)qof(v1.y,s1,z1)+128;
    int b2=(int)qof(v1.z,s1,z1)+128,b3=(int)qof(v1.w,s1,z1)+128;
    uint2 o0,o1;
    o0.x=(unsigned)lcx[off+a0]|((unsigned)lcx[off+a1]<<16);
    o0.y=(unsigned)lcx[off+a2]|((unsigned)lcx[off+a3]<<16);
    o1.x=(unsigned)lcx[off+b0]|((unsigned)lcx[off+b1]<<16);
    o1.y=(unsigned)lcx[off+b2]|((unsigned)lcx[off+b3]<<16);
    ((uint2*)catc)[e]=o0;
    ((uint2*)catc)[eb]=o1;
  }
  const float4* cp=(const float4*)c;
  unsigned* qcp=(unsigned*)qc;
  for(int e=t;e<NE/4;e+=2*stride){       // 4 unrolled-pair iters
    int eb=e+stride;
    float4 v0=cp[e],v1=cp[eb];
    int a0=(int)qof(v0.x,sc,zc)+128,a1=(int)qof(v0.y,sc,zc)+128;
    int a2=(int)qof(v0.z,sc,zc)+128,a3=(int)qof(v0.w,sc,zc)+128;
    int b0=(int)qof(v1.x,sc,zc)+128,b1=(int)qof(v1.y,sc,zc)+128;
    int b2=(int)qof(v1.z,sc,zc)+128,b3=(int)qof(v1.w,sc,zc)+128;
    qcp[e] =(unsigned)a0|((unsigned)a1<<8)|((unsigned)a2<<16)|((unsigned)a3<<24);
    qcp[eb]=(unsigned)b0|((unsigned)b1<<8)|((unsigned)b2<<16)|((unsigned)b3<<24);
  }
}

// GEMM pass A: gate pre-act minmax. grid 1024, 8 groups/block, mt fully unrolled,
// plain launch_bounds. Per-nt acc minmax with affine folded after (exact: monotone).
__global__ __launch_bounds__(256) void g0_minmax(const ushort_t* __restrict__ catc,
    const ushort_t* __restrict__ Wc,const float* __restrict__ S,
    const float* __restrict__ bq,unsigned* U){
  int tid=threadIdx.x,w=tid>>6,l=tid&63,l15=l&15,lq=l>>4;
  float sgp=S[6]*S[8+2*w];                   // s_cat * s_w[gate]
  short8 bf[4][4];
  #pragma unroll
  for(int nt=0;nt<4;nt++)
    #pragma unroll
    for(int ks=0;ks<4;ks++)
      bf[nt][ks]=*(const short8*)(Wc+w*8192+(nt*16+l15)*128+ks*32+lq*8);
  float bqr[4];
  #pragma unroll
  for(int nt=0;nt<4;nt++) bqr[nt]=bq[w*64+nt*16+l15];
  float mnA[4],mxA[4];
  #pragma unroll
  for(int nt=0;nt<4;nt++){mnA[nt]=3.4e38f;mxA[nt]=-3.4e38f;}
  for(int gi=0;gi<8;gi++){
    int rowbase=(blockIdx.x*8+gi)*64;
    #pragma unroll
    for(int mt=0;mt<4;mt++){
      const ushort_t* arow=catc+(size_t)(rowbase+mt*16+l15)*128;
      short8 af[4];
      #pragma unroll
      for(int ks=0;ks<4;ks++) af[ks]=*(const short8*)(arow+ks*32+lq*8);
      f32x4 acc[4];
      #pragma unroll
      for(int nt=0;nt<4;nt++) acc[nt]=(f32x4){0.f,0.f,0.f,0.f};
      #pragma unroll
      for(int ks=0;ks<4;ks++)
        #pragma unroll
        for(int nt=0;nt<4;nt++)
          acc[nt]=__builtin_amdgcn_mfma_f32_16x16x32_bf16(af[ks],bf[nt][ks],acc[nt],0,0,0);
      #pragma unroll
      for(int nt=0;nt<4;nt++)
        #pragma unroll
        for(int r=0;r<4;r++){
          mnA[nt]=fminf(mnA[nt],acc[nt][r]);
          mxA[nt]=fmaxf(mxA[nt],acc[nt][r]);
        }
    }
  }
  float mn=3.4e38f,mx=-3.4e38f;
  #pragma unroll
  for(int nt=0;nt<4;nt++){
    mn=fminf(mn,sgp*mnA[nt]+bqr[nt]);
    mx=fmaxf(mx,sgp*mxA[nt]+bqr[nt]);
  }
  wred(mn,mx);
  if(l==0){atomicMin(&U[6+2*w],fenc(mn));atomicMax(&U[7+2*w],fenc(mx));}
}

// GEMM pass B: quantize pre-acts to codes once, store packed codes, fc/ic minmax via LUT.
// 32-row exchange tile (padded to 66 -> <=2-way write conflicts) ~38KB LDS.
__global__ __launch_bounds__(256,2) void g1_codes(const ushort_t* __restrict__ catc,
    const ushort_t* __restrict__ Wc,const float* __restrict__ S,
    const float* __restrict__ bq,const uchar_t* __restrict__ qc,
    unsigned* U,unsigned* __restrict__ qpack,uchar_t* __restrict__ qo){
  __shared__ float ldsq[4][32][66];
  __shared__ float lut[1024];
  __shared__ float red[16];
  int tid=threadIdx.x,w=tid>>6,l=tid&63,l15=l&15,lq=l>>4;
  float sg1,zg1;
  #pragma unroll
  for(int g=0;g<4;g++){
    float s1,z1,s2,z2; stage0(U,g,s1,z1,s2,z2);
    if(g==w){sg1=s1;zg1=z1;}
    lut[g*256+tid]=lut_entry(tid,g,s1,z1,s2,z2);
  }
  float sgp=S[6]*S[8+2*w];
  float sc=S[4],zc128=S[5]+128.0f;
  short8 bf[4][4];
  #pragma unroll
  for(int nt=0;nt<4;nt++)
    #pragma unroll
    for(int ks=0;ks<4;ks++)
      bf[nt][ks]=*(const short8*)(Wc+w*8192+(nt*16+l15)*128+ks*32+lq*8);
  float bqr[4];
  #pragma unroll
  for(int nt=0;nt<4;nt++) bqr[nt]=bq[w*64+nt*16+l15];
  __syncthreads();
  float fmn=3.4e38f,fmx=-3.4e38f,imn=3.4e38f,imx=-3.4e38f;
  for(int gi=0;gi<4;gi++){
    int grp=blockIdx.x*4+gi;
    #pragma unroll
    for(int half=0;half<2;half++){
      #pragma unroll
      for(int mt2=0;mt2<2;mt2++){
        int mt=half*2+mt2;
        const ushort_t* arow=catc+(size_t)(grp*64+mt*16+l15)*128;
        short8 af[4];
        #pragma unroll
        for(int ks=0;ks<4;ks++) af[ks]=*(const short8*)(arow+ks*32+lq*8);
        f32x4 acc[4];
        #pragma unroll
        for(int nt=0;nt<4;nt++) acc[nt]=(f32x4){0.f,0.f,0.f,0.f};
        #pragma unroll
        for(int ks=0;ks<4;ks++)
          #pragma unroll
          for(int nt=0;nt<4;nt++)
            acc[nt]=__builtin_amdgcn_mfma_f32_16x16x32_bf16(af[ks],bf[nt][ks],acc[nt],0,0,0);
        #pragma unroll
        for(int nt=0;nt<4;nt++)
          #pragma unroll
          for(int r=0;r<4;r++)
            ldsq[w][mt2*16+lq*4+r][nt*16+l15]=qof(sgp*acc[nt][r]+bqr[nt],sg1,zg1);
      }
      __syncthreads();
      #pragma unroll
      for(int it=0;it<2;it++){
        int e4=(tid+it*256)<<2;                 // 0..2044 within half-tile
        int gidx=grp*4096+half*2048+e4;
        unsigned qcw=*(const unsigned*)(qc+gidx);
        uint4 qp; unsigned qob=0;
        #pragma unroll
        for(int j=0;j<4;j++){
          int row=(e4+j)>>6, col=(e4+j)&63;
          int q0=(int)ldsq[0][row][col]+128;    // i
          int q1=(int)ldsq[1][row][col]+128;    // f
          int q2=(int)ldsq[2][row][col]+128;    // o
          int q3=(int)ldsq[3][row][col]+128;    // cg
          int qcb=(int)((qcw>>(8*j))&255);
          ((unsigned*)&qp)[j]=(unsigned)q0|((unsigned)q1<<8)|((unsigned)q3<<16)|((unsigned)qcb<<24);
          qob|=(unsigned)q2<<(8*j);
          float avi=lut[q0],avf=lut[256+q1],avcg=lut[768+q3];
          float cv=((float)qcb-zc128)*sc;
          float fc=avf*cv,ic=avi*avcg;
          fmn=fminf(fmn,fc);fmx=fmaxf(fmx,fc);
          imn=fminf(imn,ic);imx=fmaxf(imx,ic);
        }
        *(uint4*)(qpack+gidx)=qp;
        *(unsigned*)(qo+gidx)=qob;
      }
      __syncthreads();
    }
  }
  wred(fmn,fmx);wred(imn,imx);
  if(l==0){red[w]=fmn;red[4+w]=fmx;red[8+w]=imn;red[12+w]=imx;}
  __syncthreads();
  if(tid==0){
    float a=fminf(fminf(red[0],red[1]),fminf(red[2],red[3]));
    float b=fmaxf(fmaxf(red[4],red[5]),fmaxf(red[6],red[7]));
    atomicMin(&U[14],fenc(a));atomicMax(&U[15],fenc(b));
    a=fminf(fminf(red[8],red[9]),fminf(red[10],red[11]));
    b=fmaxf(fmaxf(red[12],red[13]),fmaxf(red[14],red[15]));
    atomicMin(&U[16],fenc(a));atomicMax(&U[17],fenc(b));
  }
}

// elementwise: cn minmax + fc/ic codes (x4 vectorized + 2-way unrolled)
__global__ __launch_bounds__(256) void e2_cn(const unsigned* __restrict__ qpack,
    const float* __restrict__ S,unsigned* U,ushort_t* __restrict__ qfcic){
  __shared__ float lut[1024];
  __shared__ float red[8];
  int tid=threadIdx.x;
  #pragma unroll
  for(int g=0;g<4;g++){
    float s1,z1,s2,z2; stage0(U,g,s1,z1,s2,z2);
    lut[g*256+tid]=lut_entry(tid,g,s1,z1,s2,z2);
  }
  float sfc,zfc,sic,zic;
  obs(fdec(U[14]),fdec(U[15]),sfc,zfc);
  obs(fdec(U[16]),fdec(U[17]),sic,zic);
  float sc=S[4],zc128=S[5]+128.0f;
  __syncthreads();
  float mn=3.4e38f,mx=-3.4e38f;
  int t=blockIdx.x*256+tid,stride=gridDim.x*256;
  const uint4* qp4=(const uint4*)qpack;
  uint2* qf2=(uint2*)qfcic;
  for(int e=t;e<NE/4;e+=2*stride){       // grid 2048 -> 8 unrolled-pair iters
    int eb=e+stride;
    uint4 u4a=qp4[e],u4b=qp4[eb];
    uint2 oa,ob; oa.x=oa.y=ob.x=ob.y=0;
    #pragma unroll
    for(int j=0;j<4;j++){
      unsigned u=((const unsigned*)&u4a)[j];
      int q0=u&255,q1=(u>>8)&255,q3=(u>>16)&255,qcb=u>>24;
      float cv=((float)qcb-zc128)*sc;
      float fc=lut[256+q1]*cv,ic=lut[q0]*lut[768+q3];
      float qfc=qof(fc,sfc,zfc),qic=qof(ic,sic,zic);
      float cn=(qfc-zfc)*sfc+(qic-zic)*sic;
      mn=fminf(mn,cn);mx=fmaxf(mx,cn);
      unsigned pk=(unsigned)((int)qfc+128)|((unsigned)((int)qic+128)<<8);
      if(j<2) oa.x|=pk<<(16*j); else oa.y|=pk<<(16*(j-2));
    }
    #pragma unroll
    for(int j=0;j<4;j++){
      unsigned u=((const unsigned*)&u4b)[j];
      int q0=u&255,q1=(u>>8)&255,q3=(u>>16)&255,qcb=u>>24;
      float cv=((float)qcb-zc128)*sc;
      float fc=lut[256+q1]*cv,ic=lut[q0]*lut[768+q3];
      float qfc=qof(fc,sfc,zfc),qic=qof(ic,sic,zic);
      float cn=(qfc-zfc)*sfc+(qic-zic)*sic;
      mn=fminf(mn,cn);mx=fmaxf(mx,cn);
      unsigned pk=(unsigned)((int)qfc+128)|((unsigned)((int)qic+128)<<8);
      if(j<2) ob.x|=pk<<(16*j); else ob.y|=pk<<(16*(j-2));
    }
    qf2[e]=oa; qf2[eb]=ob;
  }
  int w=tid>>6,l=tid&63;
  wred(mn,mx);
  if(l==0){red[w]=mn;red[4+w]=mx;}
  __syncthreads();
  if(tid==0){
    float a=fminf(fminf(red[0],red[1]),fminf(red[2],red[3]));
    float b=fmaxf(fmaxf(red[4],red[5]),fmaxf(red[6],red[7]));
    atomicMin(&U[18],fenc(a));atomicMax(&U[19],fenc(b));
  }
}

// elementwise: c_next codes + h_raw minmax (x4 vectorized + 2-way unrolled)
__global__ __launch_bounds__(256) void e3_hmm(const ushort_t* __restrict__ qfcic,
    const uchar_t* __restrict__ qo,unsigned* U,uchar_t* __restrict__ qcn){
  __shared__ float lao[256],lct[256];
  __shared__ float red[8];
  int tid=threadIdx.x;
  {
    float s1,z1,s2,z2; stage0(U,2,s1,z1,s2,z2);
    lao[tid]=lut_entry(tid,2,s1,z1,s2,z2);
  }
  float sfc,zfc,sic,zic;
  obs(fdec(U[14]),fdec(U[15]),sfc,zfc);
  obs(fdec(U[16]),fdec(U[17]),sic,zic);
  float scn,zcn,sct,zct; stage2v(U,scn,zcn,sct,zct);
  {
    float cnv=((float)(tid-128)-zcn)*scn;
    float ct=fminf(fmaxf(cnv,-1.f),1.f);
    lct[tid]=fqv(ct,sct,zct);
  }
  float zfc128=zfc+128.0f,zic128=zic+128.0f;
  __syncthreads();
  float mn=3.4e38f,mx=-3.4e38f;
  int t=blockIdx.x*256+tid,stride=gridDim.x*256;
  const uint2* qf2=(const uint2*)qfcic;
  const unsigned* qop=(const unsigned*)qo;
  unsigned* qcp=(unsigned*)qcn;
  for(int e=t;e<NE/4;e+=2*stride){       // grid 2048 -> 8 unrolled-pair iters
    int eb=e+stride;
    uint2 ua=qf2[e],ub=qf2[eb];
    unsigned uoa=qop[e],uob=qop[eb];
    unsigned opa=0,opb=0;
    #pragma unroll
    for(int j=0;j<4;j++){
      unsigned pk=((j<2)?(ua.x>>(16*j)):(ua.y>>(16*(j-2))))&0xffffu;
      float fcv=((float)(pk&255)-zfc128)*sfc;
      float icv=((float)(pk>>8)-zic128)*sic;
      float cn=fcv+icv;
      float qcf=qof(cn,scn,zcn);
      int qb=(int)qcf+128;
      opa|=(unsigned)qb<<(8*j);
      float hr=lao[(uoa>>(8*j))&255]*lct[qb];
      mn=fminf(mn,hr);mx=fmaxf(mx,hr);
    }
    #pragma unroll
    for(int j=0;j<4;j++){
      unsigned pk=((j<2)?(ub.x>>(16*j)):(ub.y>>(16*(j-2))))&0xffffu;
      float fcv=((float)(pk&255)-zfc128)*sfc;
      float icv=((float)(pk>>8)-zic128)*sic;
      float cn=fcv+icv;
      float qcf=qof(cn,scn,zcn);
      int qb=(int)qcf+128;
      opb|=(unsigned)qb<<(8*j);
      float hr=lao[(uob>>(8*j))&255]*lct[qb];
      mn=fminf(mn,hr);mx=fmaxf(mx,hr);
    }
    qcp[e]=opa; qcp[eb]=opb;
  }
  int w=tid>>6,l=tid&63;
  wred(mn,mx);
  if(l==0){red[w]=mn;red[4+w]=mx;}
  __syncthreads();
  if(tid==0){
    float a=fminf(fminf(red[0],red[1]),fminf(red[2],red[3]));
    float b=fmaxf(fmaxf(red[4],red[5]),fmaxf(red[6],red[7]));
    atomicMin(&U[20],fenc(a));atomicMax(&U[21],fenc(b));
  }
}

// final outputs: h and c from codes + LUTs (8 elems/iter)
__global__ __launch_bounds__(256) void k9_out(const uchar_t* __restrict__ qo,
    const uchar_t* __restrict__ qcn,const unsigned* __restrict__ U,
    float* __restrict__ hout,float* __restrict__ cout){
  __shared__ float lao[256],lct[256];
  int tid=threadIdx.x;
  {
    float s1,z1,s2,z2; stage0(U,2,s1,z1,s2,z2);
    lao[tid]=lut_entry(tid,2,s1,z1,s2,z2);
  }
  float scn,zcn,sct,zct; stage2v(U,scn,zcn,sct,zct);
  {
    float cnv=((float)(tid-128)-zcn)*scn;
    float ct=fminf(fmaxf(cnv,-1.f),1.f);
    lct[tid]=fqv(ct,sct,zct);
  }
  float shn,zhn; obs(fdec(U[20]),fdec(U[21]),shn,zhn);
  float zcn128=zcn+128.0f;
  __syncthreads();
  int t=blockIdx.x*256+tid,stride=gridDim.x*256;
  const uint2* op=(const uint2*)qo;
  const uint2* cp=(const uint2*)qcn;
  float4* hp=(float4*)hout;
  float4* cpo=(float4*)cout;
  for(int e=t;e<NE/8;e+=stride){          // grid 2048 -> 8 iterations
    uint2 uo=op[e],uc=cp[e];
    float4 hv0,hv1,cv0,cv1;
    float* ph0=&hv0.x;float* pc0=&cv0.x;
    float* ph1=&hv1.x;float* pc1=&cv1.x;
    #pragma unroll
    for(int j=0;j<4;j++){
      int qoj=(uo.x>>(8*j))&255,qcj=(uc.x>>(8*j))&255;
      pc0[j]=((float)qcj-zcn128)*scn;
      float hr=lao[qoj]*lct[qcj];
      float qh=qof(hr,shn,zhn);
      ph0[j]=(qh-zhn)*shn;
    }
    #pragma unroll
    for(int j=0;j<4;j++){
      int qoj=(uo.y>>(8*j))&255,qcj=(uc.y>>(8*j))&255;
      pc1[j]=((float)qcj-zcn128)*scn;
      float hr=lao[qoj]*lct[qcj];
      float qh=qof(hr,shn,zhn);
      ph1[j]=(qh-zhn)*shn;
    }
    hp[2*e]=hv0; hp[2*e+1]=hv1;
    cpo[2*e]=cv0; cpo[2*e+1]=cv1;
  }
}

extern "C" void kernel_launch(void* const* d_in,const int* in_sizes,int n_in,
                              void* d_out,int out_size,void* d_ws,size_t ws_size,
                              hipStream_t stream){
  (void)in_sizes;(void)n_in;(void)out_size;(void)ws_size;
  const float* x  =(const float*)d_in[0];
  const float* h  =(const float*)d_in[1];
  const float* c  =(const float*)d_in[2];
  const float* Wi =(const float*)d_in[3];  const float* bi =(const float*)d_in[4];
  const float* Wf =(const float*)d_in[5];  const float* bfv=(const float*)d_in[6];
  const float* Wo =(const float*)d_in[7];  const float* bo =(const float*)d_in[8];
  const float* Wcg=(const float*)d_in[9];  const float* bcg=(const float*)d_in[10];

  char* ws=(char*)d_ws;
  unsigned* U =(unsigned*)ws;                 // 128 B
  float* S    =(float*)(ws+128);              // 256 B
  float* bq   =(float*)(ws+512);              // 1 KB
  ushort_t* LUTcx=(ushort_t*)(ws+1536);       // 1 KB cat-code LUTs (x,h)
  ushort_t* Wc=(ushort_t*)(ws+4096);          // 64 KB centered-bf16 weights
  uchar_t* qc =(uchar_t*)(ws+(1<<20));        // 32 MB c codes (biased)
  uchar_t* qo =qc +(size_t)NE;                // 32 MB o-gate codes (biased)
  uchar_t* qcn=qo +(size_t)NE;                // 32 MB c_next codes (biased)
  // d_out reuse: h-half = catc scratch (g0/g1), then qfcic (e2/e3), then h_out.
  //              c-half = qpack scratch (g1/e2), then c_out (k9).
  ushort_t* catc=(ushort_t*)d_out;
  unsigned* qpack=(unsigned*)((float*)d_out+NE);
  ushort_t* qfcic=(ushort_t*)d_out;
  float* h_out=(float*)d_out;
  float* c_out=(float*)d_out+NE;

  k0_init<<<1,64,0,stream>>>(U);
  k1_minmax<<<2048,256,0,stream>>>(x,h,c,U);
  k2_prep<<<1,256,0,stream>>>(Wi,bi,Wf,bfv,Wo,bo,Wcg,bcg,U,S,Wc,bq,LUTcx);
  k3_quant<<<2048,256,0,stream>>>(x,h,c,S,LUTcx,catc,qc);
  g0_minmax<<<1024,256,0,stream>>>(catc,Wc,S,bq,U);
  g1_codes<<<2048,256,0,stream>>>(catc,Wc,S,bq,qc,U,qpack,qo);
  e2_cn<<<2048,256,0,stream>>>(qpack,S,U,qfcic);
  e3_hmm<<<2048,256,0,stream>>>(qfcic,qo,U,qcn);
  k9_out<<<2048,256,0,stream>>>(qo,qcn,U,h_out,c_out);
}